// Round 1
// baseline (103.532 us; speedup 1.0000x reference)
//
#include <hip/hip_runtime.h>
#include <math.h>

constexpr int B  = 32;
constexpr int C  = 512;
constexpr int CR = 32;            // C / R
constexpr int HW = 56 * 56;       // 3136
constexpr int NV4 = HW / 4;       // 784 float4 per row
constexpr float EPS = 1e-5f;

// Kernel 1: per-(b,c) row sum and sum-of-squares over the 3136 spatial elems.
// One block per row; float4 loads (16B/lane); shuffle + LDS reduction.
__global__ __launch_bounds__(256) void rowstats(const float* __restrict__ x,
                                                float* __restrict__ sums,
                                                float* __restrict__ sumsq) {
    const int row = blockIdx.x;  // b*C + c
    const float4* xp = reinterpret_cast<const float4*>(x) + (size_t)row * NV4;
    float s = 0.f, q = 0.f;
    for (int i = threadIdx.x; i < NV4; i += 256) {
        float4 v = xp[i];
        s += (v.x + v.y) + (v.z + v.w);
        q += (v.x * v.x + v.y * v.y) + (v.z * v.z + v.w * v.w);
    }
    // wave-64 butterfly-style down-reduce
    #pragma unroll
    for (int off = 32; off > 0; off >>= 1) {
        s += __shfl_down(s, off, 64);
        q += __shfl_down(q, off, 64);
    }
    __shared__ float ls[4], lq[4];
    const int wid = threadIdx.x >> 6, lane = threadIdx.x & 63;
    if (lane == 0) { ls[wid] = s; lq[wid] = q; }
    __syncthreads();
    if (threadIdx.x == 0) {
        sums[row]  = (ls[0] + ls[1]) + (ls[2] + ls[3]);
        sumsq[row] = (lq[0] + lq[1]) + (lq[2] + lq[3]);
    }
}

// Kernel 2: everything else. One block, 512 threads, 72 KB LDS.
__global__ __launch_bounds__(512) void fuse(const float* __restrict__ sums,
                                            const float* __restrict__ sumsq,
                                            const float* __restrict__ w1,
                                            const float* __restrict__ w2,
                                            const float* __restrict__ bnw,
                                            const float* __restrict__ bnb,
                                            float* __restrict__ out) {
    __shared__ float sh_s[B][C];    // holds s, then m = e*s in place
    __shared__ float sh_h[B][CR];
    __shared__ float sh_mean[C];
    __shared__ float sh_g[C];
    const int tid = threadIdx.x;
    constexpr float invHW = 1.0f / (float)HW;

    // s[b][c] = mean over h,w
    for (int i = tid; i < B * C; i += 512)
        sh_s[i >> 9][i & (C - 1)] = sums[i] * invHW;
    __syncthreads();

    // h[b][j] = relu(sum_c s[b][c] * w1[j][c])   (B*CR = 1024 dots of 512)
    for (int p = tid; p < B * CR; p += 512) {
        const int b = p >> 5, j = p & (CR - 1);
        const float* w1r = w1 + j * C;
        float acc = 0.f;
        #pragma unroll 8
        for (int c = 0; c < C; ++c) acc = fmaf(sh_s[b][c], w1r[c], acc);
        sh_h[b][j] = fmaxf(acc, 0.f);
    }
    __syncthreads();

    // Per channel c (one thread each): e, m, BN stats, scale factor.
    {
        const int c = tid;           // 512 threads == C channels
        float w2r[CR];
        #pragma unroll
        for (int j = 0; j < CR; ++j) w2r[j] = w2[c * CR + j];
        float mean = 0.f, eq = 0.f;
        for (int b = 0; b < B; ++b) {
            float acc = 0.f;
            #pragma unroll
            for (int j = 0; j < CR; ++j) acc = fmaf(sh_h[b][j], w2r[j], acc);
            const float e = 1.0f / (1.0f + expf(-acc));
            const float m = e * sh_s[b][c];
            sh_s[b][c] = m;          // only this thread touches (.,c)
            mean += m;
            eq = fmaf(e * e, sumsq[b * C + c], eq);
        }
        mean *= (1.0f / (float)B);
        const float var = eq * (1.0f / ((float)B * (float)HW)) - mean * mean;
        sh_mean[c] = mean;
        sh_g[c]    = bnw[c] * rsqrtf(var + EPS);
    }
    __syncthreads();

    // out[b][c2] = sum_{c1 in {0,1}} (m[b][c1*256+c2] - mean)*g + bias
    for (int i = tid; i < B * (C / 2); i += 512) {
        const int b = i >> 8, c2 = i & (C / 2 - 1);
        const int ca = c2, cb = (C / 2) + c2;
        const float za = (sh_s[b][ca] - sh_mean[ca]) * sh_g[ca] + bnb[ca];
        const float zb = (sh_s[b][cb] - sh_mean[cb]) * sh_g[cb] + bnb[cb];
        out[i] = za + zb;
    }
}

extern "C" void kernel_launch(void* const* d_in, const int* in_sizes, int n_in,
                              void* d_out, int out_size, void* d_ws, size_t ws_size,
                              hipStream_t stream) {
    const float* x   = (const float*)d_in[0];
    const float* w1  = (const float*)d_in[1];
    const float* w2  = (const float*)d_in[2];
    const float* bnw = (const float*)d_in[3];
    const float* bnb = (const float*)d_in[4];
    float* out = (float*)d_out;

    float* sums  = (float*)d_ws;          // B*C floats
    float* sumsq = sums + B * C;          // B*C floats  (128 KB total)

    rowstats<<<dim3(B * C), dim3(256), 0, stream>>>(x, sums, sumsq);
    fuse<<<dim3(1), dim3(512), 0, stream>>>(sums, sumsq, w1, w2, bnw, bnb, out);
}

// Round 2
// 60.117 us; speedup vs baseline: 1.7222x; 1.7222x over previous
//
#include <hip/hip_runtime.h>
#include <math.h>

constexpr int B  = 32;
constexpr int C  = 512;
constexpr int CR = 32;            // C / R
constexpr int HW = 56 * 56;       // 3136
constexpr int NV4 = HW / 4;       // 784 float4 per row
constexpr int CP = C + 4;         // padded LDS stride (516): float4-aligned, 4-way worst case
constexpr float EPS = 1e-5f;

// Kernel 1: one wave per (b,c) row. 12 unrolled float4 loads/lane + 16-lane tail,
// shuffle-only reduction (no LDS, no syncthreads). Writes s = mean and sum(x^2).
__global__ __launch_bounds__(256) void rowstats(const float* __restrict__ x,
                                                float* __restrict__ s_out,
                                                float* __restrict__ q_out) {
    const int wid  = threadIdx.x >> 6;
    const int lane = threadIdx.x & 63;
    const int row  = blockIdx.x * 4 + wid;          // grid = 4096 -> 16384 rows
    const float4* xp = reinterpret_cast<const float4*>(x) + (size_t)row * NV4 + lane;
    float s = 0.f, q = 0.f;
    #pragma unroll
    for (int i = 0; i < 12; ++i) {                   // 12*64 = 768 float4
        float4 v = xp[i * 64];
        s += (v.x + v.y) + (v.z + v.w);
        q += (v.x * v.x + v.y * v.y) + (v.z * v.z + v.w * v.w);
    }
    if (lane < 16) {                                 // tail: 784 - 768 = 16
        float4 v = xp[768];
        s += (v.x + v.y) + (v.z + v.w);
        q += (v.x * v.x + v.y * v.y) + (v.z * v.z + v.w * v.w);
    }
    #pragma unroll
    for (int off = 32; off > 0; off >>= 1) {
        s += __shfl_down(s, off, 64);
        q += __shfl_down(q, off, 64);
    }
    if (lane == 0) {
        s_out[row] = s * (1.0f / (float)HW);
        q_out[row] = q;
    }
}

// Kernel 2: everything else. One block, 512 threads.
// LDS: s (padded) + w1 (coalesced staged) + h + mean/g  ~= 138 KB (< 160 KB/CU).
__global__ __launch_bounds__(512) void fuse(const float* __restrict__ s_in,
                                            const float* __restrict__ sumsq,
                                            const float* __restrict__ w1,
                                            const float* __restrict__ w2,
                                            const float* __restrict__ bnw,
                                            const float* __restrict__ bnb,
                                            float* __restrict__ out) {
    __shared__ __align__(16) float sh_s[B][CP];      // s, then m = e*s in place
    __shared__ __align__(16) float sh_w1[CR][C];
    __shared__ float sh_h[B][CR + 1];
    __shared__ float sh_mean[C];
    __shared__ float sh_g[C];
    const int tid = threadIdx.x;

    // --- Prefetch per-channel data into registers (coalesced), hide under stages A/B.
    const int c = tid;                               // 512 threads == C channels
    float w2r[CR];
    {
        const float4* w2p = reinterpret_cast<const float4*>(w2) + c * (CR / 4);
        #pragma unroll
        for (int k = 0; k < CR / 4; ++k)
            reinterpret_cast<float4*>(w2r)[k] = w2p[k];
    }
    float sqr[B];
    #pragma unroll
    for (int b = 0; b < B; ++b) sqr[b] = sumsq[b * C + c];   // coalesced per b

    // --- Stage A: cooperative loads into LDS (all coalesced).
    for (int i = tid; i < B * C; i += 512)
        sh_s[i >> 9][i & (C - 1)] = s_in[i];
    {
        const float4* w1p = reinterpret_cast<const float4*>(w1);
        float4* dst = reinterpret_cast<float4*>(&sh_w1[0][0]);
        for (int i = tid; i < CR * C / 4; i += 512) dst[i] = w1p[i];
    }
    __syncthreads();

    // --- Stage B: h[b][j] = relu(s[b]·w1[j]).  j uniform per half-wave (w1 broadcast),
    // b varies across lanes (padded sh_s -> cheap). Two (b,j) pairs per thread.
    for (int p = tid; p < B * CR; p += 512) {
        const int b = p & (B - 1), j = p >> 5;
        const float4* sr = reinterpret_cast<const float4*>(&sh_s[b][0]);
        const float4* wr = reinterpret_cast<const float4*>(&sh_w1[j][0]);
        float a0 = 0.f, a1 = 0.f;
        #pragma unroll 8
        for (int k = 0; k < C / 4; k += 2) {
            float4 sv = sr[k], wv = wr[k];
            a0 = fmaf(sv.x, wv.x, fmaf(sv.y, wv.y, fmaf(sv.z, wv.z, fmaf(sv.w, wv.w, a0))));
            float4 s2 = sr[k + 1], w2v = wr[k + 1];
            a1 = fmaf(s2.x, w2v.x, fmaf(s2.y, w2v.y, fmaf(s2.z, w2v.z, fmaf(s2.w, w2v.w, a1))));
        }
        sh_h[b][j] = fmaxf(a0 + a1, 0.f);
    }
    __syncthreads();

    // --- Stage C: per channel c: e = sigmoid(h·w2[c]), m = e*s, BN stats.
    {
        float mean = 0.f, eq = 0.f;
        #pragma unroll 4
        for (int b = 0; b < B; ++b) {
            float acc = 0.f;
            #pragma unroll
            for (int j = 0; j < CR; ++j) acc = fmaf(sh_h[b][j], w2r[j], acc);  // LDS broadcast
            const float e = 1.0f / (1.0f + expf(-acc));
            const float m = e * sh_s[b][c];
            sh_s[b][c] = m;                          // only thread c touches column c
            mean += m;
            eq = fmaf(e * e, sqr[b], eq);
        }
        mean *= (1.0f / (float)B);
        const float var = eq * (1.0f / ((float)B * (float)HW)) - mean * mean;
        sh_mean[c] = mean;
        sh_g[c]    = bnw[c] * rsqrtf(var + EPS);
    }
    __syncthreads();

    // --- Stage D: out[b][c2] = sum_{c1} (m - mean)*g + bias over the two halves.
    for (int i = tid; i < B * (C / 2); i += 512) {
        const int b = i >> 8, c2 = i & (C / 2 - 1);
        const int cb = (C / 2) + c2;
        const float za = (sh_s[b][c2] - sh_mean[c2]) * sh_g[c2] + bnb[c2];
        const float zb = (sh_s[b][cb] - sh_mean[cb]) * sh_g[cb] + bnb[cb];
        out[i] = za + zb;
    }
}

extern "C" void kernel_launch(void* const* d_in, const int* in_sizes, int n_in,
                              void* d_out, int out_size, void* d_ws, size_t ws_size,
                              hipStream_t stream) {
    const float* x   = (const float*)d_in[0];
    const float* w1  = (const float*)d_in[1];
    const float* w2  = (const float*)d_in[2];
    const float* bnw = (const float*)d_in[3];
    const float* bnb = (const float*)d_in[4];
    float* out = (float*)d_out;

    float* s_ws  = (float*)d_ws;          // B*C floats (s = row means)
    float* q_ws  = s_ws + B * C;          // B*C floats (row sum of squares)

    rowstats<<<dim3(B * C / 4), dim3(256), 0, stream>>>(x, s_ws, q_ws);
    fuse<<<dim3(1), dim3(512), 0, stream>>>(s_ws, q_ws, w1, w2, bnw, bnb, out);
}

// Round 3
// 42.603 us; speedup vs baseline: 2.4302x; 1.4111x over previous
//
#include <hip/hip_runtime.h>
#include <math.h>

constexpr int B  = 32;
constexpr int C  = 512;
constexpr int CR = 32;            // C / R
constexpr int HW = 56 * 56;       // 3136
constexpr int NV4 = HW / 4;       // 784 float4 per row
constexpr float EPS = 1e-5f;

// Kernel 1: one wave per (b,c) row. 12 unrolled float4 loads/lane + 16-lane tail,
// shuffle-only reduction. Writes s = mean and q = sum(x^2).
__global__ __launch_bounds__(256) void rowstats(const float* __restrict__ x,
                                                float* __restrict__ s_out,
                                                float* __restrict__ q_out) {
    const int wid  = threadIdx.x >> 6;
    const int lane = threadIdx.x & 63;
    const int row  = blockIdx.x * 4 + wid;          // grid = 4096 -> 16384 rows
    const float4* xp = reinterpret_cast<const float4*>(x) + (size_t)row * NV4 + lane;
    float s = 0.f, q = 0.f;
    #pragma unroll
    for (int i = 0; i < 12; ++i) {                   // 12*64 = 768 float4
        float4 v = xp[i * 64];
        s += (v.x + v.y) + (v.z + v.w);
        q += (v.x * v.x + v.y * v.y) + (v.z * v.z + v.w * v.w);
    }
    if (lane < 16) {                                 // tail: 784 - 768 = 16
        float4 v = xp[768];
        s += (v.x + v.y) + (v.z + v.w);
        q += (v.x * v.x + v.y * v.y) + (v.z * v.z + v.w * v.w);
    }
    #pragma unroll
    for (int off = 32; off > 0; off >>= 1) {
        s += __shfl_down(s, off, 64);
        q += __shfl_down(q, off, 64);
    }
    if (lane == 0) {
        s_out[row] = s * (1.0f / (float)HW);
        q_out[row] = q;
    }
}

// Kernel 2: SE excitation, one block per batch element b (32 blocks, 512 threads).
// Writes m[b][c] = e*s and eq[b][c] = e^2 * sum(x^2).
__global__ __launch_bounds__(512) void excite(const float* __restrict__ s_in,
                                              const float* __restrict__ q_in,
                                              const float* __restrict__ w1,
                                              const float* __restrict__ w2,
                                              float* __restrict__ m_out,
                                              float* __restrict__ eq_out) {
    const int b   = blockIdx.x;
    const int tid = threadIdx.x;
    __shared__ __align__(16) float sh_s[C];
    __shared__ float sh_h[CR];

    sh_s[tid] = s_in[b * C + tid];                   // coalesced
    __syncthreads();

    // h[j] = relu(dot(s, w1[j])): 16 threads per j (tid = j*16 + t).
    {
        const int j = tid >> 4, t = tid & 15;
        const float4* wr = reinterpret_cast<const float4*>(w1 + j * C);
        const float4* sr = reinterpret_cast<const float4*>(sh_s);
        float acc = 0.f;
        #pragma unroll
        for (int k = 0; k < 8; ++k) {                // 8 * 16 = 128 float4 = 512 floats
            float4 wv = wr[t + 16 * k];
            float4 sv = sr[t + 16 * k];
            acc = fmaf(sv.x, wv.x, fmaf(sv.y, wv.y, fmaf(sv.z, wv.z, fmaf(sv.w, wv.w, acc))));
        }
        #pragma unroll
        for (int off = 8; off > 0; off >>= 1)
            acc += __shfl_down(acc, off, 16);
        if (t == 0) sh_h[j] = fmaxf(acc, 0.f);
    }
    __syncthreads();

    // e[c] = sigmoid(dot(h, w2[c])) per thread c; emit m and eq.
    {
        const int c = tid;
        const float4* w2p = reinterpret_cast<const float4*>(w2 + c * CR);
        const float4* hp  = reinterpret_cast<const float4*>(sh_h);
        float acc = 0.f;
        #pragma unroll
        for (int k = 0; k < CR / 4; ++k) {
            float4 wv = w2p[k];
            float4 hv = hp[k];                       // LDS broadcast
            acc = fmaf(hv.x, wv.x, fmaf(hv.y, wv.y, fmaf(hv.z, wv.z, fmaf(hv.w, wv.w, acc))));
        }
        const float e = 1.0f / (1.0f + expf(-acc));
        m_out[b * C + c]  = e * sh_s[c];
        eq_out[b * C + c] = e * e * q_in[b * C + c];
    }
}

// Kernel 3: BN stats + final combine. One block, 512 threads (thread = channel c).
__global__ __launch_bounds__(512) void bnout(const float* __restrict__ m_in,
                                             const float* __restrict__ eq_in,
                                             const float* __restrict__ bnw,
                                             const float* __restrict__ bnb,
                                             float* __restrict__ out) {
    const int c = threadIdx.x;
    __shared__ float sh_z[B][C / 2];                 // first-half normalized vals
    float mv[B];
    float mean = 0.f, eq = 0.f;
    #pragma unroll
    for (int b = 0; b < B; ++b) {                    // coalesced, L2-hit
        mv[b] = m_in[b * C + c];
        mean += mv[b];
        eq   += eq_in[b * C + c];
    }
    mean *= (1.0f / (float)B);
    const float var = eq * (1.0f / ((float)B * (float)HW)) - mean * mean;
    const float g   = bnw[c] * rsqrtf(var + EPS);
    const float bb  = bnb[c];

    if (c < C / 2) {
        #pragma unroll
        for (int b = 0; b < B; ++b)
            sh_z[b][c] = (mv[b] - mean) * g + bb;
    }
    __syncthreads();
    if (c >= C / 2) {
        const int c2 = c - C / 2;
        #pragma unroll
        for (int b = 0; b < B; ++b)
            out[b * (C / 2) + c2] = sh_z[b][c2] + ((mv[b] - mean) * g + bb);
    }
}

extern "C" void kernel_launch(void* const* d_in, const int* in_sizes, int n_in,
                              void* d_out, int out_size, void* d_ws, size_t ws_size,
                              hipStream_t stream) {
    const float* x   = (const float*)d_in[0];
    const float* w1  = (const float*)d_in[1];
    const float* w2  = (const float*)d_in[2];
    const float* bnw = (const float*)d_in[3];
    const float* bnb = (const float*)d_in[4];
    float* out = (float*)d_out;

    float* s_ws  = (float*)d_ws;          // B*C floats (row means)
    float* q_ws  = s_ws + B * C;          // B*C floats (row sum of squares)
    float* m_ws  = q_ws + B * C;          // B*C floats (e*s)
    float* eq_ws = m_ws + B * C;          // B*C floats (e^2 * sumsq)

    rowstats<<<dim3(B * C / 4), dim3(256), 0, stream>>>(x, s_ws, q_ws);
    excite<<<dim3(B), dim3(512), 0, stream>>>(s_ws, q_ws, w1, w2, m_ws, eq_ws);
    bnout<<<dim3(1), dim3(512), 0, stream>>>(m_ws, eq_ws, bnw, bnb, out);
}